// Round 1
// baseline (174.004 us; speedup 1.0000x reference)
//
#include <hip/hip_runtime.h>

using f32x4 = __attribute__((ext_vector_type(4))) float;
using f32x2 = __attribute__((ext_vector_type(2))) float;
using bf16x8 = __attribute__((ext_vector_type(8))) short;

#define MFMA(a, b, c) __builtin_amdgcn_mfma_f32_16x16x32_bf16(a, b, c, 0, 0, 0)

__device__ __forceinline__ unsigned short f2bf(float f) {
    union { float f; unsigned u; } c; c.f = f;
    unsigned u = c.u;
    u += 0x7fffu + ((u >> 16) & 1u);
    return (unsigned short)(u >> 16);
}
__device__ __forceinline__ float bf2f(unsigned short s) {
    union { unsigned u; float f; } c; c.u = ((unsigned)s) << 16; return c.f;
}
__device__ __forceinline__ unsigned pack2(float a, float b) {
    return (unsigned)f2bf(a) | ((unsigned)f2bf(b) << 16);
}

// ---------------------------------------------------------------------------
// K1: q/k/v projections. C[i,n] = nodes[i,:] @ W[n,:] + b[n]; q scaled 0.125.
// q,k -> bf16 [1024][512]; v -> transposed bf16 [512][1024]
// ---------------------------------------------------------------------------
__global__ __launch_bounds__(256) void k_qkv(
    const float* __restrict__ nodes,
    const float* __restrict__ Wq, const float* __restrict__ bq,
    const float* __restrict__ Wk, const float* __restrict__ bk,
    const float* __restrict__ Wv, const float* __restrict__ bv,
    unsigned short* __restrict__ qbf, unsigned short* __restrict__ kbf,
    unsigned short* __restrict__ vt)
{
    const int kind = blockIdx.z;
    const float* W = (kind == 0) ? Wq : ((kind == 1) ? Wk : Wv);
    const float* bias = (kind == 0) ? bq : ((kind == 1) ? bk : bv);
    const int i0 = blockIdx.x * 64, n0 = blockIdx.y * 64;
    const int t = threadIdx.x, lane = t & 63, w = t >> 6;
    const int l15 = lane & 15, l4 = lane >> 4;
    __shared__ __align__(16) unsigned short sA[64 * 72];
    __shared__ __align__(16) unsigned short sB[64 * 72];
    f32x4 acc[2][2] = {};
    const int wr = (w >> 1) * 32, wc = (w & 1) * 32;
    const int r = t >> 2, q4 = t & 3;
    for (int kb = 0; kb < 512; kb += 64) {
        for (int k = 0; k < 4; k++) {
            int col = k * 16 + q4 * 4;
            f32x4 av = *(const f32x4*)(nodes + (i0 + r) * 512 + kb + col);
            f32x4 bv_ = *(const f32x4*)(W + (n0 + r) * 512 + kb + col);
            uint2 pa; pa.x = pack2(av.x, av.y); pa.y = pack2(av.z, av.w);
            uint2 pb; pb.x = pack2(bv_.x, bv_.y); pb.y = pack2(bv_.z, bv_.w);
            *(uint2*)(sA + r * 72 + col) = pa;
            *(uint2*)(sB + r * 72 + col) = pb;
        }
        __syncthreads();
        for (int ks = 0; ks < 2; ks++) {
            bf16x8 a0 = *(const bf16x8*)(sA + (wr + l15) * 72 + ks * 32 + l4 * 8);
            bf16x8 a1 = *(const bf16x8*)(sA + (wr + 16 + l15) * 72 + ks * 32 + l4 * 8);
            bf16x8 b0 = *(const bf16x8*)(sB + (wc + l15) * 72 + ks * 32 + l4 * 8);
            bf16x8 b1 = *(const bf16x8*)(sB + (wc + 16 + l15) * 72 + ks * 32 + l4 * 8);
            acc[0][0] = MFMA(a0, b0, acc[0][0]);
            acc[0][1] = MFMA(a0, b1, acc[0][1]);
            acc[1][0] = MFMA(a1, b0, acc[1][0]);
            acc[1][1] = MFMA(a1, b1, acc[1][1]);
        }
        __syncthreads();
    }
    const float scale = (kind == 0) ? 0.125f : 1.0f;
    for (int fi = 0; fi < 2; fi++) for (int fj = 0; fj < 2; fj++)
        for (int rr = 0; rr < 4; rr++) {
            int i = i0 + wr + fi * 16 + l4 * 4 + rr;
            int n = n0 + wc + fj * 16 + l15;
            float v = (acc[fi][fj][rr] + bias[n]) * scale;
            if (kind == 0) qbf[i * 512 + n] = f2bf(v);
            else if (kind == 1) kbf[i * 512 + n] = f2bf(v);
            else vt[n * 1024 + i] = f2bf(v);
        }
}

// ---------------------------------------------------------------------------
// K2: node-node scores S[h][i][j] = q[i, h*64:] . k[j, h*64:]   (fp32 out)
// ---------------------------------------------------------------------------
__global__ __launch_bounds__(256) void k_scores(
    const unsigned short* __restrict__ qbf, const unsigned short* __restrict__ kbf,
    float* __restrict__ S)
{
    const int h = blockIdx.z, i0 = blockIdx.x * 64, j0 = blockIdx.y * 64;
    const int t = threadIdx.x, lane = t & 63, w = t >> 6;
    const int l15 = lane & 15, l4 = lane >> 4;
    __shared__ __align__(16) unsigned short sQ[64 * 72];
    __shared__ __align__(16) unsigned short sK[64 * 72];
    const int r = t >> 2, q4 = t & 3;
    for (int k = 0; k < 2; k++) {
        int col = k * 32 + q4 * 8;
        uint4 aq = *(const uint4*)(qbf + (i0 + r) * 512 + h * 64 + col);
        uint4 ak = *(const uint4*)(kbf + (j0 + r) * 512 + h * 64 + col);
        *(uint4*)(sQ + r * 72 + col) = aq;
        *(uint4*)(sK + r * 72 + col) = ak;
    }
    __syncthreads();
    f32x4 acc[2][2] = {};
    const int wr = (w >> 1) * 32, wc = (w & 1) * 32;
    for (int ks = 0; ks < 2; ks++) {
        bf16x8 a0 = *(const bf16x8*)(sQ + (wr + l15) * 72 + ks * 32 + l4 * 8);
        bf16x8 a1 = *(const bf16x8*)(sQ + (wr + 16 + l15) * 72 + ks * 32 + l4 * 8);
        bf16x8 b0 = *(const bf16x8*)(sK + (wc + l15) * 72 + ks * 32 + l4 * 8);
        bf16x8 b1 = *(const bf16x8*)(sK + (wc + 16 + l15) * 72 + ks * 32 + l4 * 8);
        acc[0][0] = MFMA(a0, b0, acc[0][0]);
        acc[0][1] = MFMA(a0, b1, acc[0][1]);
        acc[1][0] = MFMA(a1, b0, acc[1][0]);
        acc[1][1] = MFMA(a1, b1, acc[1][1]);
    }
    for (int fi = 0; fi < 2; fi++) for (int fj = 0; fj < 2; fj++)
        for (int rr = 0; rr < 4; rr++) {
            long i = i0 + wr + fi * 16 + l4 * 4 + rr;
            int j = j0 + wc + fj * 16 + l15;
            S[((long)h << 20) + i * 1024 + j] = acc[fi][fj][rr];
        }
}

// ---------------------------------------------------------------------------
// K3: fused per-node-row attention core.
// One WG per node i. Streams edge row, LN -> struct_k/struct_v via MFMA,
// struct scores via MFMA, mask + online softmax, struct-PV via MFMA.
// Writes normalized P (bf16) and struct output (fp32).
// ---------------------------------------------------------------------------
__global__ __launch_bounds__(256) void k_attn(
    const float* __restrict__ edges, const int* __restrict__ maskp,
    const float* __restrict__ S, const unsigned short* __restrict__ qbf,
    const float* __restrict__ Wsk, const float* __restrict__ bsk,
    const float* __restrict__ Wsv, const float* __restrict__ bsv,
    const float* __restrict__ png, const float* __restrict__ pnb,
    unsigned short* __restrict__ P, float* __restrict__ outs)
{
    const int i = blockIdx.x;
    const int t = threadIdx.x;
    const int lane = t & 63, w = t >> 6;
    const int l15 = lane & 15, l4 = lane >> 4;

    __shared__ float s_scores[8 * 1028];
    __shared__ __align__(16) unsigned short s_ln[64 * 72];
    __shared__ __align__(16) unsigned short s_sk[64 * 72];
    __shared__ __align__(16) unsigned short s_svt[64 * 72];
    __shared__ __align__(16) unsigned short s_p8[16 * 72];
    __shared__ __align__(16) unsigned short s_q8[16 * 72];
    __shared__ float s_m[16], s_l[16], s_scale[16], s_qbsk[8];

    // ---- init: q8 (rows 0-7 = scaled q, 8-15 zero), p8 zero, m/l/scale, q.bsk
    {
        int hh = t >> 4, dd = (t & 15) * 4;
        uint2 v; v.x = 0; v.y = 0;
        if (hh < 8) v = *(const uint2*)(qbf + i * 512 + hh * 64 + dd);
        *(uint2*)(s_q8 + hh * 72 + dd) = v;
        uint2 z; z.x = 0; z.y = 0;
        *(uint2*)(s_p8 + hh * 72 + dd) = z;
    }
    if (t < 16) { s_m[t] = -1e30f; s_l[t] = 0.f; s_scale[t] = 1.f; }
    if (t < 8) {
        float a = 0.f;
        for (int d = 0; d < 64; d++) a += bf2f(qbf[i * 512 + t * 64 + d]) * bsk[d];
        s_qbsk[t] = a;
    }

    // ---- hoist Wsk/Wsv fragments into registers (constant over tiles)
    bf16x8 wsk[2][4], wsv[2][4];
    for (int ks = 0; ks < 2; ks++) for (int ob = 0; ob < 4; ob++) {
        const float* p1 = Wsk + (ob * 16 + l15) * 64 + ks * 32 + l4 * 8;
        f32x4 x0 = *(const f32x4*)p1; f32x4 x1 = *(const f32x4*)(p1 + 4);
        bf16x8 f;
        f[0] = f2bf(x0.x); f[1] = f2bf(x0.y); f[2] = f2bf(x0.z); f[3] = f2bf(x0.w);
        f[4] = f2bf(x1.x); f[5] = f2bf(x1.y); f[6] = f2bf(x1.z); f[7] = f2bf(x1.w);
        wsk[ks][ob] = f;
        const float* p2 = Wsv + (ob * 16 + l15) * 64 + ks * 32 + l4 * 8;
        f32x4 y0 = *(const f32x4*)p2; f32x4 y1 = *(const f32x4*)(p2 + 4);
        bf16x8 g;
        g[0] = f2bf(y0.x); g[1] = f2bf(y0.y); g[2] = f2bf(y0.z); g[3] = f2bf(y0.w);
        g[4] = f2bf(y1.x); g[5] = f2bf(y1.y); g[6] = f2bf(y1.z); g[7] = f2bf(y1.w);
        wsv[ks][ob] = g;
    }
    const int dcol = (t & 15) * 4;
    const f32x4 g4 = *(const f32x4*)(png + dcol);
    const f32x4 b4 = *(const f32x4*)(pnb + dcol);

    __syncthreads();

    bf16x8 aq[2];
    for (int ks = 0; ks < 2; ks++)
        aq[ks] = *(const bf16x8*)(s_q8 + l15 * 72 + ks * 32 + l4 * 8);

    const float* erow = edges + (long)i * 65536;
    f32x4 ereg[4];
    for (int k = 0; k < 4; k++) ereg[k] = *(const f32x4*)(erow + k * 1024 + t * 4);

    f32x4 acc; acc[0] = acc[1] = acc[2] = acc[3] = 0.f;

    for (int tt = 0; tt < 16; tt++) {
        const int j0 = tt * 64;
        f32x4 enext[4];
        if (tt < 15)
            for (int k = 0; k < 4; k++)
                enext[k] = *(const f32x4*)(erow + (j0 + 64) * 64 + k * 1024 + t * 4);

        // ---- phase 1a: LayerNorm of 64 edge rows (thread holds 4 rows x 4 cols)
        float s1[4], s2[4];
        for (int k = 0; k < 4; k++) {
            f32x4 e = ereg[k];
            s1[k] = e.x + e.y + e.z + e.w;
            s2[k] = e.x * e.x + e.y * e.y + e.z * e.z + e.w * e.w;
        }
        for (int m = 1; m < 16; m <<= 1)
            for (int k = 0; k < 4; k++) {
                s1[k] += __shfl_xor(s1[k], m);
                s2[k] += __shfl_xor(s2[k], m);
            }
        for (int k = 0; k < 4; k++) {
            float mean = s1[k] * (1.f / 64.f);
            float var = s2[k] * (1.f / 64.f) - mean * mean;
            float rs = rsqrtf(var + 1e-5f);
            f32x4 e = ereg[k];
            float y0 = (e.x - mean) * rs * g4.x + b4.x;
            float y1 = (e.y - mean) * rs * g4.y + b4.y;
            float y2 = (e.z - mean) * rs * g4.z + b4.z;
            float y3 = (e.w - mean) * rs * g4.w + b4.w;
            int row = k * 16 + (t >> 4);
            uint2 pv; pv.x = pack2(y0, y1); pv.y = pack2(y2, y3);
            *(uint2*)(s_ln + row * 72 + dcol) = pv;
        }
        // ---- phase 1b: node scores + mask + q.bsk -> scores LDS
        {
            int h = t >> 5, jj = (t & 31) * 2;
            const float* Sp = S + ((long)h << 20) + (long)i * 1024 + j0 + jj;
            f32x2 sv2 = *(const f32x2*)Sp;
            int2 mk = *(const int2*)(maskp + i * 1024 + j0 + jj);
            float qb = s_qbsk[h];
            s_scores[h * 1028 + j0 + jj] = (mk.x == 0) ? -1e9f : (sv2.x + qb);
            s_scores[h * 1028 + j0 + jj + 1] = (mk.y == 0) ? -1e9f : (sv2.y + qb);
        }
        __syncthreads();
        // ---- phase 3: struct_k / struct_v projection MFMA (wave w -> 16 j rows)
        {
            bf16x8 a0 = *(const bf16x8*)(s_ln + (w * 16 + l15) * 72 + l4 * 8);
            bf16x8 a1 = *(const bf16x8*)(s_ln + (w * 16 + l15) * 72 + 32 + l4 * 8);
            for (int ob = 0; ob < 4; ob++) {
                f32x4 ck; ck[0] = ck[1] = ck[2] = ck[3] = 0.f;
                f32x4 cv; cv[0] = cv[1] = cv[2] = cv[3] = 0.f;
                ck = MFMA(a0, wsk[0][ob], ck); ck = MFMA(a1, wsk[1][ob], ck);
                cv = MFMA(a0, wsv[0][ob], cv); cv = MFMA(a1, wsv[1][ob], cv);
                for (int rr = 0; rr < 4; rr++) {
                    int jl = w * 16 + l4 * 4 + rr;
                    s_sk[jl * 72 + ob * 16 + l15] = f2bf(ck[rr]);
                    s_svt[(ob * 16 + l15) * 72 + jl] = f2bf(cv[rr]);
                }
            }
        }
        __syncthreads();
        // ---- phase 4: struct scores MFMA (heads on M), RMW into scores
        {
            bf16x8 b0 = *(const bf16x8*)(s_sk + (w * 16 + l15) * 72 + l4 * 8);
            bf16x8 b1 = *(const bf16x8*)(s_sk + (w * 16 + l15) * 72 + 32 + l4 * 8);
            f32x4 c; c[0] = c[1] = c[2] = c[3] = 0.f;
            c = MFMA(aq[0], b0, c); c = MFMA(aq[1], b1, c);
            if (lane < 32)
                for (int rr = 0; rr < 4; rr++) {
                    int h = l4 * 4 + rr;
                    s_scores[h * 1028 + j0 + w * 16 + l15] += c[rr];
                }
        }
        __syncthreads();
        // ---- phase 5: online softmax tile update
        {
            int h = t >> 5, s32 = t & 31;
            int j = j0 + s32 * 2;
            float a0 = s_scores[h * 1028 + j], a1 = s_scores[h * 1028 + j + 1];
            float mx = fmaxf(a0, a1);
            for (int m = 1; m < 32; m <<= 1) mx = fmaxf(mx, __shfl_xor(mx, m));
            float m_old = s_m[h];
            float m_new = fmaxf(m_old, mx);
            float p0 = __expf(a0 - m_new), p1 = __expf(a1 - m_new);
            *(unsigned*)(s_p8 + h * 72 + s32 * 2) = pack2(p0, p1);
            float ps = p0 + p1;
            for (int m = 1; m < 32; m <<= 1) ps += __shfl_xor(ps, m);
            if (s32 == 0) {
                float sg = __expf(m_old - m_new);
                s_scale[h] = sg;
                s_l[h] = s_l[h] * sg + ps;
                s_m[h] = m_new;
            }
        }
        __syncthreads();
        // ---- phase 6: struct-PV MFMA (wave w -> d-block w), online rescale
        {
            float sc0 = s_scale[l4 * 4 + 0];
            float sc1 = s_scale[l4 * 4 + 1];
            float sc2 = s_scale[l4 * 4 + 2];
            float sc3 = s_scale[l4 * 4 + 3];
            acc[0] *= sc0; acc[1] *= sc1; acc[2] *= sc2; acc[3] *= sc3;
            bf16x8 ap0 = *(const bf16x8*)(s_p8 + l15 * 72 + l4 * 8);
            bf16x8 ap1 = *(const bf16x8*)(s_p8 + l15 * 72 + 32 + l4 * 8);
            bf16x8 bv0 = *(const bf16x8*)(s_svt + (w * 16 + l15) * 72 + l4 * 8);
            bf16x8 bv1 = *(const bf16x8*)(s_svt + (w * 16 + l15) * 72 + 32 + l4 * 8);
            acc = MFMA(ap0, bv0, acc);
            acc = MFMA(ap1, bv1, acc);
        }
        if (tt < 15)
            for (int k = 0; k < 4; k++) ereg[k] = enext[k];
    }

    // ---- epilogue: final normalized P
    for (int h = 0; h < 8; h++) {
        float mh = s_m[h];
        float il = 1.0f / s_l[h];
        for (int kk = 0; kk < 4; kk++) {
            int j = kk * 256 + t;
            float p = __expf(s_scores[h * 1028 + j] - mh) * il;
            P[((long)h << 20) + (long)i * 1024 + j] = f2bf(p);
        }
    }
    // ---- struct output (+ bsv since sum(P)=1)
    if (lane < 32) {
        for (int rr = 0; rr < 4; rr++) {
            int h = l4 * 4 + rr;
            float il = 1.0f / s_l[h];
            int d = w * 16 + l15;
            outs[i * 512 + h * 64 + d] = acc[rr] * il + bsv[d];
        }
    }
}

// ---------------------------------------------------------------------------
// K4: node PV: out[h, i, d] = P[h,i,:] @ v[h,:,d]; add struct out; bf16 out.
// ---------------------------------------------------------------------------
__global__ __launch_bounds__(64) void k_pv(
    const unsigned short* __restrict__ P, const unsigned short* __restrict__ vt,
    const float* __restrict__ outs, unsigned short* __restrict__ attn_bf)
{
    const int h = blockIdx.y;
    const int i0 = blockIdx.x * 16;
    const int lane = threadIdx.x;
    const int l15 = lane & 15, l4 = lane >> 4;
    const unsigned short* Ph = P + ((long)h << 20);
    const unsigned short* vh = vt + h * 64 * 1024;
    f32x4 acc[4] = {};
    for (int ks = 0; ks < 32; ks++) {
        bf16x8 a = *(const bf16x8*)(Ph + (i0 + l15) * 1024 + ks * 32 + l4 * 8);
        for (int ob = 0; ob < 4; ob++) {
            bf16x8 b = *(const bf16x8*)(vh + (ob * 16 + l15) * 1024 + ks * 32 + l4 * 8);
            acc[ob] = MFMA(a, b, acc[ob]);
        }
    }
    for (int ob = 0; ob < 4; ob++)
        for (int rr = 0; rr < 4; rr++) {
            int i = i0 + l4 * 4 + rr;
            int col = h * 64 + ob * 16 + l15;
            attn_bf[i * 512 + col] = f2bf(acc[ob][rr] + outs[i * 512 + col]);
        }
}

// ---------------------------------------------------------------------------
// K5: output projection + bias + relu + residual (fp32 z)
// ---------------------------------------------------------------------------
__global__ __launch_bounds__(256) void k_out(
    const unsigned short* __restrict__ attn_bf, const float* __restrict__ Wo,
    const float* __restrict__ bo, const float* __restrict__ nodes,
    float* __restrict__ z)
{
    const int i0 = blockIdx.x * 64, n0 = blockIdx.y * 64;
    const int t = threadIdx.x, lane = t & 63, w = t >> 6;
    const int l15 = lane & 15, l4 = lane >> 4;
    __shared__ __align__(16) unsigned short sA[64 * 72];
    __shared__ __align__(16) unsigned short sB[64 * 72];
    f32x4 acc[2][2] = {};
    const int wr = (w >> 1) * 32, wc = (w & 1) * 32;
    const int r = t >> 2, q4 = t & 3;
    for (int kb = 0; kb < 512; kb += 64) {
        for (int k = 0; k < 2; k++) {
            int col = k * 32 + q4 * 8;
            uint4 aa = *(const uint4*)(attn_bf + (i0 + r) * 512 + kb + col);
            *(uint4*)(sA + r * 72 + col) = aa;
        }
        for (int k = 0; k < 4; k++) {
            int col = k * 16 + q4 * 4;
            f32x4 bv_ = *(const f32x4*)(Wo + (n0 + r) * 512 + kb + col);
            uint2 pb; pb.x = pack2(bv_.x, bv_.y); pb.y = pack2(bv_.z, bv_.w);
            *(uint2*)(sB + r * 72 + col) = pb;
        }
        __syncthreads();
        for (int ks = 0; ks < 2; ks++) {
            bf16x8 a0 = *(const bf16x8*)(sA + (wr + l15) * 72 + ks * 32 + l4 * 8);
            bf16x8 a1 = *(const bf16x8*)(sA + (wr + 16 + l15) * 72 + ks * 32 + l4 * 8);
            bf16x8 b0 = *(const bf16x8*)(sB + (wc + l15) * 72 + ks * 32 + l4 * 8);
            bf16x8 b1 = *(const bf16x8*)(sB + (wc + 16 + l15) * 72 + ks * 32 + l4 * 8);
            acc[0][0] = MFMA(a0, b0, acc[0][0]);
            acc[0][1] = MFMA(a0, b1, acc[0][1]);
            acc[1][0] = MFMA(a1, b0, acc[1][0]);
            acc[1][1] = MFMA(a1, b1, acc[1][1]);
        }
        __syncthreads();
    }
    for (int fi = 0; fi < 2; fi++) for (int fj = 0; fj < 2; fj++)
        for (int rr = 0; rr < 4; rr++) {
            int i = i0 + wr + fi * 16 + l4 * 4 + rr;
            int n = n0 + wc + fj * 16 + l15;
            float v = fmaxf(acc[fi][fj][rr] + bo[n], 0.f);
            z[i * 512 + n] = nodes[i * 512 + n] + v;
        }
}

// ---------------------------------------------------------------------------
// K6: final LayerNorm over 512, fp32 out. One wave per row.
// ---------------------------------------------------------------------------
__global__ __launch_bounds__(256) void k_ln(
    const float* __restrict__ z, const float* __restrict__ g,
    const float* __restrict__ b, float* __restrict__ out)
{
    const int row = blockIdx.x * 4 + (threadIdx.x >> 6);
    const int lane = threadIdx.x & 63;
    const float* zp = z + row * 512;
    f32x4 x0 = *(const f32x4*)(zp + lane * 4);
    f32x4 x1 = *(const f32x4*)(zp + 256 + lane * 4);
    float s = x0.x + x0.y + x0.z + x0.w + x1.x + x1.y + x1.z + x1.w;
    float ss = x0.x * x0.x + x0.y * x0.y + x0.z * x0.z + x0.w * x0.w
             + x1.x * x1.x + x1.y * x1.y + x1.z * x1.z + x1.w * x1.w;
    for (int m = 1; m < 64; m <<= 1) { s += __shfl_xor(s, m); ss += __shfl_xor(ss, m); }
    float mean = s * (1.f / 512.f);
    float var = ss * (1.f / 512.f) - mean * mean;
    float rs = rsqrtf(var + 1e-5f);
    f32x4 g0 = *(const f32x4*)(g + lane * 4);
    f32x4 g1 = *(const f32x4*)(g + 256 + lane * 4);
    f32x4 b0 = *(const f32x4*)(b + lane * 4);
    f32x4 b1 = *(const f32x4*)(b + 256 + lane * 4);
    f32x4 o0, o1;
    o0.x = (x0.x - mean) * rs * g0.x + b0.x;
    o0.y = (x0.y - mean) * rs * g0.y + b0.y;
    o0.z = (x0.z - mean) * rs * g0.z + b0.z;
    o0.w = (x0.w - mean) * rs * g0.w + b0.w;
    o1.x = (x1.x - mean) * rs * g1.x + b1.x;
    o1.y = (x1.y - mean) * rs * g1.y + b1.y;
    o1.z = (x1.z - mean) * rs * g1.z + b1.z;
    o1.w = (x1.w - mean) * rs * g1.w + b1.w;
    *(f32x4*)(out + row * 512 + lane * 4) = o0;
    *(f32x4*)(out + row * 512 + 256 + lane * 4) = o1;
}

// ---------------------------------------------------------------------------
extern "C" void kernel_launch(void* const* d_in, const int* in_sizes, int n_in,
                              void* d_out, int out_size, void* d_ws, size_t ws_size,
                              hipStream_t stream)
{
    const float* nodes = (const float*)d_in[0];
    const float* edges = (const float*)d_in[1];
    const int* mask = (const int*)d_in[2];
    const float* Wq = (const float*)d_in[3]; const float* bq = (const float*)d_in[4];
    const float* Wk = (const float*)d_in[5]; const float* bk = (const float*)d_in[6];
    const float* Wv = (const float*)d_in[7]; const float* bv = (const float*)d_in[8];
    const float* Wsk = (const float*)d_in[9]; const float* bsk = (const float*)d_in[10];
    const float* Wsv = (const float*)d_in[11]; const float* bsv = (const float*)d_in[12];
    const float* Wo = (const float*)d_in[13]; const float* bo = (const float*)d_in[14];
    const float* png = (const float*)d_in[15]; const float* pnb = (const float*)d_in[16];
    const float* lng = (const float*)d_in[17]; const float* lnb = (const float*)d_in[18];
    float* out = (float*)d_out;

    char* ws = (char*)d_ws;
    unsigned short* qbf = (unsigned short*)(ws + 0);                 // 1 MB
    unsigned short* kbf = (unsigned short*)(ws + (1u << 20));        // 1 MB
    unsigned short* vt = (unsigned short*)(ws + (2u << 20));         // 1 MB
    float* S = (float*)(ws + (4u << 20));                            // 32 MB
    unsigned short* P = (unsigned short*)(ws + (36u << 20));         // 16 MB
    float* outs = (float*)(ws + (52u << 20));                        // 2 MB
    unsigned short* attn_bf = (unsigned short*)(ws + (54u << 20));   // 1 MB
    float* z = (float*)(ws + (55u << 20));                           // 2 MB

    k_qkv<<<dim3(16, 8, 3), 256, 0, stream>>>(nodes, Wq, bq, Wk, bk, Wv, bv,
                                              qbf, kbf, vt);
    k_scores<<<dim3(16, 16, 8), 256, 0, stream>>>(qbf, kbf, S);
    k_attn<<<dim3(1024), 256, 0, stream>>>(edges, mask, S, qbf, Wsk, bsk,
                                           Wsv, bsv, png, pnb, P, outs);
    k_pv<<<dim3(64, 8), 64, 0, stream>>>(P, vt, outs, attn_bf);
    k_out<<<dim3(16, 8), 256, 0, stream>>>(attn_bf, Wo, bo, nodes, z);
    k_ln<<<dim3(256), 256, 0, stream>>>(z, lng, lnb, out);
}